// Round 1
// baseline (1013.159 us; speedup 1.0000x reference)
//
#include <hip/hip_runtime.h>

#define D_IN 1024
#define HID  2048
#define KSEL 32

typedef __attribute__((ext_vector_type(8))) short short8;
typedef __attribute__((ext_vector_type(4))) float f32x4;

__device__ __forceinline__ short f2bf(float f) {
  union { float f; unsigned u; } c; c.f = f;
  unsigned u = c.u;
  unsigned r = (u + 0x7fffu + ((u >> 16) & 1u)) >> 16;  // RNE
  return (short)(r & 0xffffu);
}

// ---------------------------------------------------------------------------
// Pre-pass 1: x (2048x1024 fp32) -> bf16 A-panels laid out per (mt, ks) tile
// in exact LDS staging order: Apanel[mt][ks][m(128)][k(32)]
// ---------------------------------------------------------------------------
__global__ __launch_bounds__(256) void conv_x_kernel(const float* __restrict__ x,
                                                     short* __restrict__ Apanel) {
  int tid = blockIdx.x * 256 + threadIdx.x;   // 0..262143, each does 8 elems
  int k8 = tid & 3;
  int m  = (tid >> 2) & 127;
  int ks = (tid >> 9) & 31;
  int mt = tid >> 14;
  const float* src = x + (size_t)(mt * 128 + m) * D_IN + ks * 32 + k8 * 8;
  short8 v;
#pragma unroll
  for (int j = 0; j < 8; ++j) v[j] = f2bf(src[j]);
  *(short8*)(Apanel + (size_t)tid * 8) = v;   // offset == tid*8 by construction
}

// ---------------------------------------------------------------------------
// Pre-pass 2: gather W1[subset] (fp32), transpose d<->h, convert to bf16,
// write B^T panels: Bpanel[kk][nt][ks][n(128)][d(32)]  (128 MiB)
// One block per (kk, nt, ks): reads a 32(d) x 128(h) fp32 tile.
// ---------------------------------------------------------------------------
__global__ __launch_bounds__(256) void conv_w1_kernel(const float* __restrict__ W1,
                                                      const int* __restrict__ subset,
                                                      short* __restrict__ Bpanel) {
  int bid = blockIdx.x;                 // 32*16*32 = 16384 blocks
  int ks = bid & 31;
  int nt = (bid >> 5) & 15;
  int kk = bid >> 9;
  int p  = subset[kk];
  __shared__ float tile[32][129];       // +1 pad to break transpose conflicts
  int t = threadIdx.x;
  const float* src = W1 + ((size_t)p * D_IN + ks * 32) * HID + nt * 128;
#pragma unroll
  for (int i = 0; i < 4; ++i) {
    int dl = i * 8 + (t >> 5);          // d row 0..31
    int hl = (t & 31) * 4;              // h col, float4
    float4 v = *(const float4*)(src + (size_t)dl * HID + hl);
    tile[dl][hl] = v.x; tile[dl][hl + 1] = v.y;
    tile[dl][hl + 2] = v.z; tile[dl][hl + 3] = v.w;
  }
  __syncthreads();
  short* dst = Bpanel + (size_t)((kk * 16 + nt) * 32 + ks) * 4096;
#pragma unroll
  for (int j = 0; j < 2; ++j) {
    int n  = j * 64 + (t >> 2);         // h within tile
    int d8 = (t & 3) * 8;               // d chunk
    short8 v;
#pragma unroll
    for (int dd = 0; dd < 8; ++dd) v[dd] = f2bf(tile[d8 + dd][n]);
    *(short8*)(dst + n * 32 + d8) = v;  // offset == j*2048 + t*8 : coalesced
  }
}

// ---------------------------------------------------------------------------
// Init: out[b][k] = b2[subset[k]]  (atomics accumulate on top)
// ---------------------------------------------------------------------------
__global__ __launch_bounds__(256) void init_out_kernel(const int* __restrict__ subset,
                                                       const float* __restrict__ b2,
                                                       float* __restrict__ out) {
  int i = blockIdx.x * 256 + threadIdx.x;  // 65536
  out[i] = b2[subset[i & 31]];
}

// ---------------------------------------------------------------------------
// Main fused GEMM: per block (mt, nt, kk): 128x128 tile of x @ W1[s_kk],
// relu+b1 epilogue, dot with W2, shuffle-reduce over n, atomicAdd to out.
// ---------------------------------------------------------------------------
__device__ __forceinline__ void load_lds16(const short* g, short* l) {
  __builtin_amdgcn_global_load_lds((const __attribute__((address_space(1))) void*)g,
                                   (__attribute__((address_space(3))) void*)l,
                                   16, 0, 0);
}

__global__ __launch_bounds__(256) void gemm_kernel(const short* __restrict__ Apanel,
                                                   const short* __restrict__ Bpanel,
                                                   const int* __restrict__ subset,
                                                   const float* __restrict__ b1,
                                                   const float* __restrict__ W2,
                                                   float* __restrict__ out) {
  __shared__ __align__(16) short Atile[4096];   // 128 m x 32 k
  __shared__ __align__(16) short Btile[4096];   // 128 n x 32 k (B^T)

  // XCD-aware swizzle: each XCD owns a 4-wide kk range -> 16 MiB B working set
  int id = blockIdx.x;
  int xcd = id & 7;
  int chunk = id >> 3;                 // 0..1023
  int kk = xcd * 4 + (chunk >> 8);
  int nt = (chunk >> 4) & 15;
  int mt = chunk & 15;

  int tid  = threadIdx.x;
  int wave = tid >> 6;
  int lane = tid & 63;
  int wm = wave >> 1, wn = wave & 1;   // 2x2 wave grid, 64x64 each
  int ml = lane & 15;                  // m (A) / n (B) within 16-tile
  int kq = lane >> 4;                  // k-quad

  const short* Abase = Apanel + (size_t)mt * (32 * 4096);
  const short* Bbase = Bpanel + (size_t)((kk * 16 + nt)) * (32 * 4096);

  short* AldsBase0 = Atile + (wave * 64) * 8;
  short* AldsBase1 = Atile + (256 + wave * 64) * 8;
  short* BldsBase0 = Btile + (wave * 64) * 8;
  short* BldsBase1 = Btile + (256 + wave * 64) * 8;

  f32x4 acc[4][4] = {};

  const short8* Ar = (const short8*)Atile;
  const short8* Br = (const short8*)Btile;
  int arow = wm * 64 + ml;
  int brow = wn * 64 + ml;

  for (int ks = 0; ks < 32; ++ks) {
    const short* ga = Abase + ks * 4096;
    const short* gb = Bbase + ks * 4096;
    load_lds16(ga + tid * 8,         AldsBase0);
    load_lds16(ga + (256 + tid) * 8, AldsBase1);
    load_lds16(gb + tid * 8,         BldsBase0);
    load_lds16(gb + (256 + tid) * 8, BldsBase1);
    __syncthreads();   // compiler emits vmcnt(0) drain here

    short8 a[4], b[4];
#pragma unroll
    for (int ti = 0; ti < 4; ++ti) a[ti] = Ar[(arow + ti * 16) * 4 + kq];
#pragma unroll
    for (int tj = 0; tj < 4; ++tj) b[tj] = Br[(brow + tj * 16) * 4 + kq];
#pragma unroll
    for (int ti = 0; ti < 4; ++ti)
#pragma unroll
      for (int tj = 0; tj < 4; ++tj)
        acc[ti][tj] = __builtin_amdgcn_mfma_f32_16x16x32_bf16(a[ti], b[tj],
                                                              acc[ti][tj], 0, 0, 0);
    __syncthreads();
  }

  // Epilogue: h = relu(acc + b1[n]); partial[m] = sum_n h * W2[n]
  int sk = subset[kk];
  const float* b1p = b1 + (size_t)sk * HID + nt * 128 + wn * 64;
  const float* w2p = W2 + (size_t)sk * HID + nt * 128 + wn * 64;
  float b1v[4], w2v[4];
#pragma unroll
  for (int tj = 0; tj < 4; ++tj) {
    int n = tj * 16 + ml;
    b1v[tj] = b1p[n];
    w2v[tj] = w2p[n];
  }
  float part[4][4];
#pragma unroll
  for (int ti = 0; ti < 4; ++ti)
#pragma unroll
    for (int r = 0; r < 4; ++r) {
      float s = 0.f;
#pragma unroll
      for (int tj = 0; tj < 4; ++tj) {
        float h = acc[ti][tj][r] + b1v[tj];
        h = h > 0.f ? h : 0.f;
        s += h * w2v[tj];
      }
      part[ti][r] = s;
    }
  // reduce over the 16 n-lanes (C-layout col = lane&15)
#pragma unroll
  for (int off = 1; off < 16; off <<= 1) {
#pragma unroll
    for (int ti = 0; ti < 4; ++ti)
#pragma unroll
      for (int r = 0; r < 4; ++r)
        part[ti][r] += __shfl_xor(part[ti][r], off, 64);
  }
  if (ml == 0) {
    int mbase = mt * 128 + wm * 64 + kq * 4;   // C-layout row = kq*4 + r
#pragma unroll
    for (int ti = 0; ti < 4; ++ti)
#pragma unroll
      for (int r = 0; r < 4; ++r)
        atomicAdd(out + (size_t)(mbase + ti * 16 + r) * KSEL + kk, part[ti][r]);
  }
}

// ---------------------------------------------------------------------------
extern "C" void kernel_launch(void* const* d_in, const int* in_sizes, int n_in,
                              void* d_out, int out_size, void* d_ws, size_t ws_size,
                              hipStream_t stream) {
  const float* x      = (const float*)d_in[0];
  const int*   subset = (const int*)d_in[1];
  const float* W1     = (const float*)d_in[2];
  const float* b1     = (const float*)d_in[3];
  const float* W2     = (const float*)d_in[4];
  const float* b2     = (const float*)d_in[5];
  float* out = (float*)d_out;

  short* Apanel = (short*)d_ws;                                  // 4 MiB
  short* Bpanel = (short*)((char*)d_ws + (size_t)4 * 1024 * 1024); // 128 MiB

  conv_x_kernel<<<1024, 256, 0, stream>>>(x, Apanel);
  conv_w1_kernel<<<16384, 256, 0, stream>>>(W1, subset, Bpanel);
  init_out_kernel<<<256, 256, 0, stream>>>(subset, b2, out);
  gemm_kernel<<<8192, 256, 0, stream>>>(Apanel, Bpanel, subset, b1, W2, out);
}

// Round 2
// 988.977 us; speedup vs baseline: 1.0245x; 1.0245x over previous
//
#include <hip/hip_runtime.h>

#define D_IN 1024
#define HID  2048
#define KSEL 32

typedef __attribute__((ext_vector_type(8))) short short8;
typedef __attribute__((ext_vector_type(4))) float f32x4;

__device__ __forceinline__ short f2bf(float f) {
  union { float f; unsigned u; } c; c.f = f;
  unsigned u = c.u;
  unsigned r = (u + 0x7fffu + ((u >> 16) & 1u)) >> 16;  // RNE
  return (short)(r & 0xffffu);
}

__device__ __forceinline__ void load_lds16(const void* g, void* l) {
  __builtin_amdgcn_global_load_lds((const __attribute__((address_space(1))) void*)g,
                                   (__attribute__((address_space(3))) void*)l,
                                   16, 0, 0);
}

// ---------------------------------------------------------------------------
// Pre-pass 1: x (2048x1024 fp32) -> bf16 A-panels in exact LDS staging order:
// Apanel[mt][ks][m(128)][k(32)]
// ---------------------------------------------------------------------------
__global__ __launch_bounds__(256) void conv_x_kernel(const float* __restrict__ x,
                                                     short* __restrict__ Apanel) {
  int tid = blockIdx.x * 256 + threadIdx.x;   // 0..262143, each does 8 elems
  int k8 = tid & 3;
  int m  = (tid >> 2) & 127;
  int ks = (tid >> 9) & 31;
  int mt = tid >> 14;
  const float* src = x + (size_t)(mt * 128 + m) * D_IN + ks * 32 + k8 * 8;
  short8 v;
#pragma unroll
  for (int j = 0; j < 8; ++j) v[j] = f2bf(src[j]);
  *(short8*)(Apanel + (size_t)tid * 8) = v;   // offset == tid*8 by construction
}

// ---------------------------------------------------------------------------
// Pre-pass 2 (v2): gather W1[subset] fp32, transpose d<->h, cvt bf16, write
// B^T panels Bpanel[kk][nt][ks][n(128)][d(32)].
// One FAT block per (kk, ks): reads a fully CONTIGUOUS 256 KB region
// (32 consecutive d-rows x 2048 h), 8 h-chunks of 256 staged via
// global_load_lds (each instr = 1 KB contiguous), writes 16 x 8 KB
// contiguous bf16 panels. 1024 blocks = 4/CU.
// ---------------------------------------------------------------------------
__global__ __launch_bounds__(256) void conv_w1_kernel(const float* __restrict__ W1,
                                                      const int* __restrict__ subset,
                                                      short* __restrict__ Bpanel) {
  int bid = blockIdx.x;                 // 1024 = 32 kk * 32 ks
  int ks = bid & 31;
  int kk = bid >> 5;
  int p  = subset[kk];
  __shared__ __align__(16) float tile[32][260];   // 33 KB, stride 260 (mod32=4)
  int t = threadIdx.x;
  int wave = t >> 6, lane = t & 63;
  const float* src = W1 + ((size_t)p * D_IN + ks * 32) * HID;  // 32 rows x 2048
  short* dstbase = Bpanel + (size_t)(kk * 16) * (32 * 4096) + (size_t)ks * 4096;

  for (int hc = 0; hc < 8; ++hc) {
    // load 32 rows x 256 floats; one global_load_lds per (wave,row):
    // 64 lanes x 16B = 1 KB contiguous global read -> contiguous LDS row
#pragma unroll
    for (int rr = 0; rr < 8; ++rr) {
      int row = rr * 4 + wave;          // wave-uniform
      const float* g = src + (size_t)row * HID + hc * 256 + lane * 4;
      load_lds16(g, &tile[row][0]);
    }
    __syncthreads();
    // transpose-write 2 nt panels (h-chunk 256 = 2 x 128)
#pragma unroll
    for (int j = 0; j < 2; ++j) {
      int nt = hc * 2 + j;
      int n  = t >> 1;                  // 0..127
      int kh = (t & 1) * 16;            // 0 or 16
      int col = j * 128 + n;
      short8 v0, v1;
#pragma unroll
      for (int dd = 0; dd < 8; ++dd) v0[dd] = f2bf(tile[kh + dd][col]);
#pragma unroll
      for (int dd = 0; dd < 8; ++dd) v1[dd] = f2bf(tile[kh + 8 + dd][col]);
      short* dst = dstbase + (size_t)nt * (32 * 4096) + n * 32 + kh;
      *(short8*)dst = v0;               // thread t writes bytes [t*32, t*32+32)
      *(short8*)(dst + 8) = v1;         // of the 8 KB panel: fully contiguous
    }
    __syncthreads();
  }
}

// ---------------------------------------------------------------------------
// Init: out[b][k] = b2[subset[k]]  (atomics accumulate on top)
// ---------------------------------------------------------------------------
__global__ __launch_bounds__(256) void init_out_kernel(const int* __restrict__ subset,
                                                       const float* __restrict__ b2,
                                                       float* __restrict__ out) {
  int i = blockIdx.x * 256 + threadIdx.x;  // 65536
  out[i] = b2[subset[i & 31]];
}

// ---------------------------------------------------------------------------
// Main fused GEMM (unchanged from R1): per block (mt, nt, kk): 128x128 tile,
// relu+b1 epilogue, dot with W2, shuffle-reduce over n, atomicAdd to out.
// ---------------------------------------------------------------------------
__global__ __launch_bounds__(256) void gemm_kernel(const short* __restrict__ Apanel,
                                                   const short* __restrict__ Bpanel,
                                                   const int* __restrict__ subset,
                                                   const float* __restrict__ b1,
                                                   const float* __restrict__ W2,
                                                   float* __restrict__ out) {
  __shared__ __align__(16) short Atile[4096];   // 128 m x 32 k
  __shared__ __align__(16) short Btile[4096];   // 128 n x 32 k (B^T)

  int id = blockIdx.x;
  int xcd = id & 7;
  int chunk = id >> 3;                 // 0..1023
  int kk = xcd * 4 + (chunk >> 8);
  int nt = (chunk >> 4) & 15;
  int mt = chunk & 15;

  int tid  = threadIdx.x;
  int wave = tid >> 6;
  int lane = tid & 63;
  int wm = wave >> 1, wn = wave & 1;   // 2x2 wave grid, 64x64 each
  int ml = lane & 15;
  int kq = lane >> 4;

  const short* Abase = Apanel + (size_t)mt * (32 * 4096);
  const short* Bbase = Bpanel + (size_t)((kk * 16 + nt)) * (32 * 4096);

  short* AldsBase0 = Atile + (wave * 64) * 8;
  short* AldsBase1 = Atile + (256 + wave * 64) * 8;
  short* BldsBase0 = Btile + (wave * 64) * 8;
  short* BldsBase1 = Btile + (256 + wave * 64) * 8;

  f32x4 acc[4][4] = {};

  const short8* Ar = (const short8*)Atile;
  const short8* Br = (const short8*)Btile;
  int arow = wm * 64 + ml;
  int brow = wn * 64 + ml;

  for (int ks = 0; ks < 32; ++ks) {
    const short* ga = Abase + ks * 4096;
    const short* gb = Bbase + ks * 4096;
    load_lds16(ga + tid * 8,         AldsBase0);
    load_lds16(ga + (256 + tid) * 8, AldsBase1);
    load_lds16(gb + tid * 8,         BldsBase0);
    load_lds16(gb + (256 + tid) * 8, BldsBase1);
    __syncthreads();

    short8 a[4], b[4];
#pragma unroll
    for (int ti = 0; ti < 4; ++ti) a[ti] = Ar[(arow + ti * 16) * 4 + kq];
#pragma unroll
    for (int tj = 0; tj < 4; ++tj) b[tj] = Br[(brow + tj * 16) * 4 + kq];
#pragma unroll
    for (int ti = 0; ti < 4; ++ti)
#pragma unroll
      for (int tj = 0; tj < 4; ++tj)
        acc[ti][tj] = __builtin_amdgcn_mfma_f32_16x16x32_bf16(a[ti], b[tj],
                                                              acc[ti][tj], 0, 0, 0);
    __syncthreads();
  }

  int sk = subset[kk];
  const float* b1p = b1 + (size_t)sk * HID + nt * 128 + wn * 64;
  const float* w2p = W2 + (size_t)sk * HID + nt * 128 + wn * 64;
  float b1v[4], w2v[4];
#pragma unroll
  for (int tj = 0; tj < 4; ++tj) {
    int n = tj * 16 + ml;
    b1v[tj] = b1p[n];
    w2v[tj] = w2p[n];
  }
  float part[4][4];
#pragma unroll
  for (int ti = 0; ti < 4; ++ti)
#pragma unroll
    for (int r = 0; r < 4; ++r) {
      float s = 0.f;
#pragma unroll
      for (int tj = 0; tj < 4; ++tj) {
        float h = acc[ti][tj][r] + b1v[tj];
        h = h > 0.f ? h : 0.f;
        s += h * w2v[tj];
      }
      part[ti][r] = s;
    }
#pragma unroll
  for (int off = 1; off < 16; off <<= 1) {
#pragma unroll
    for (int ti = 0; ti < 4; ++ti)
#pragma unroll
      for (int r = 0; r < 4; ++r)
        part[ti][r] += __shfl_xor(part[ti][r], off, 64);
  }
  if (ml == 0) {
    int mbase = mt * 128 + wm * 64 + kq * 4;
#pragma unroll
    for (int ti = 0; ti < 4; ++ti)
#pragma unroll
      for (int r = 0; r < 4; ++r)
        atomicAdd(out + (size_t)(mbase + ti * 16 + r) * KSEL + kk, part[ti][r]);
  }
}

// ---------------------------------------------------------------------------
extern "C" void kernel_launch(void* const* d_in, const int* in_sizes, int n_in,
                              void* d_out, int out_size, void* d_ws, size_t ws_size,
                              hipStream_t stream) {
  const float* x      = (const float*)d_in[0];
  const int*   subset = (const int*)d_in[1];
  const float* W1     = (const float*)d_in[2];
  const float* b1     = (const float*)d_in[3];
  const float* W2     = (const float*)d_in[4];
  const float* b2     = (const float*)d_in[5];
  float* out = (float*)d_out;

  short* Apanel = (short*)d_ws;                                    // 4 MiB
  short* Bpanel = (short*)((char*)d_ws + (size_t)4 * 1024 * 1024); // 128 MiB

  conv_x_kernel<<<1024, 256, 0, stream>>>(x, Apanel);
  conv_w1_kernel<<<1024, 256, 0, stream>>>(W1, subset, Bpanel);
  init_out_kernel<<<256, 256, 0, stream>>>(subset, b2, out);
  gemm_kernel<<<8192, 256, 0, stream>>>(Apanel, Bpanel, subset, b1, W2, out);
}